// Round 2
// baseline (116.273 us; speedup 1.0000x reference)
//
#include <hip/hip_runtime.h>

// CrossingNumberLoss: count edge pairs (i<j) with |cos(angle between them)| > 0.1,
// normalized by E*(E-1)/2.
//
// Strategy: brute-force E x E tiled pair count on the vector ALU (K=2 dot product
// -> MFMA is useless here). Each block recomputes the normalized edge vectors for
// its row strip (registers) and column strip (LDS) — pos (64 KiB) and edge_index
// (128 KiB int32) are L2-resident, so recompute beats staging ev[] in workspace
// and needs zero scratch. Single unsigned accumulator lives in d_out itself.

#define BLK 256   // threads per block
#define IPT 2     // rows per thread  -> 512 rows per block
#define TJ  512   // cols per block (LDS tile)
#define THR 0.1f

__device__ __forceinline__ float2 edge_vec(const float* __restrict__ pos,
                                           const int* __restrict__ eidx,
                                           int E, int i) {
    int s = eidx[i];        // edge_index[0][i]
    int t = eidx[E + i];    // edge_index[1][i]
    float dx = pos[2 * t]     - pos[2 * s];
    float dy = pos[2 * t + 1] - pos[2 * s + 1];
    float n  = sqrtf(dx * dx + dy * dy);
    float cn = fmaxf(n, 1e-6f);            // jnp.clip(norm, 1e-6)
    return make_float2(dx / cn, dy / cn);
}

__global__ __launch_bounds__(BLK) void count_kernel(const float* __restrict__ pos,
                                                    const int* __restrict__ eidx,
                                                    unsigned* __restrict__ total,
                                                    int E) {
    __shared__ float txs[TJ], tys[TJ];
    int tid = threadIdx.x;
    int rowBase = blockIdx.x * (BLK * IPT);
    int colBase = blockIdx.y * TJ;

    // column strip -> LDS (zero vector never counts: dot = 0 <= THR)
    for (int j = tid; j < TJ; j += BLK) {
        int jj = colBase + j;
        float2 v = (jj < E) ? edge_vec(pos, eidx, E, jj) : make_float2(0.f, 0.f);
        txs[j] = v.x;
        tys[j] = v.y;
    }
    __syncthreads();

    // row strip -> registers
    float xi[IPT], yi[IPT];
    int   ri[IPT];
#pragma unroll
    for (int k = 0; k < IPT; ++k) {
        ri[k] = rowBase + k * BLK + tid;
        float2 v = (ri[k] < E) ? edge_vec(pos, eidx, E, ri[k]) : make_float2(0.f, 0.f);
        xi[k] = v.x;
        yi[k] = v.y;
    }

    int cnt = 0;
    bool hasDiag = (rowBase < colBase + TJ) && (colBase < rowBase + BLK * IPT);
    if (!hasDiag) {
        // hot path: 992 of 1024 blocks, no diagonal test
#pragma unroll 4
        for (int j = 0; j < TJ; ++j) {
            float tx = txs[j];   // broadcast LDS read, conflict-free
            float ty = tys[j];
#pragma unroll
            for (int k = 0; k < IPT; ++k) {
                float d = xi[k] * tx + yi[k] * ty;
                cnt += (fabsf(d) > THR) ? 1 : 0;
            }
        }
    } else {
        // diagonal blocks: skip j == i pairs inline (replaces diag_hits subtraction)
#pragma unroll 4
        for (int j = 0; j < TJ; ++j) {
            float tx = txs[j];
            float ty = tys[j];
            int jj = colBase + j;
#pragma unroll
            for (int k = 0; k < IPT; ++k) {
                float d = xi[k] * tx + yi[k] * ty;
                cnt += ((fabsf(d) > THR) && (jj != ri[k])) ? 1 : 0;
            }
        }
    }

    // wave(64) shuffle reduction, one atomic per wave
    for (int off = 32; off > 0; off >>= 1)
        cnt += __shfl_down(cnt, off);
    if ((tid & 63) == 0)
        atomicAdd(total, (unsigned)cnt);
}

// Ordered off-diagonal hit count u is exactly even (cos_ij == cos_ji bitwise).
// result = (u/2) / (E*(E-1)/2)
__global__ void finalize_kernel(unsigned* __restrict__ acc, int E) {
    unsigned u = acc[0];
    double count = (double)u * 0.5;
    double denom = (double)E * (double)(E - 1) * 0.5;
    ((float*)acc)[0] = (float)(count / denom);
}

extern "C" void kernel_launch(void* const* d_in, const int* in_sizes, int n_in,
                              void* d_out, int out_size, void* d_ws, size_t ws_size,
                              hipStream_t stream) {
    const float* pos  = (const float*)d_in[0];   // [8192, 2] f32
    const int*   eidx = (const int*)d_in[1];     // [2, E], harness passes integers as int32
    int E = in_sizes[1] / 2;

    unsigned* acc = (unsigned*)d_out;            // reuse d_out as the accumulator
    hipMemsetAsync(d_out, 0, sizeof(unsigned), stream);

    dim3 grid((E + BLK * IPT - 1) / (BLK * IPT), (E + TJ - 1) / TJ);
    count_kernel<<<grid, BLK, 0, stream>>>(pos, eidx, acc, E);

    finalize_kernel<<<1, 1, 0, stream>>>(acc, E);
}

// Round 4
// 101.049 us; speedup vs baseline: 1.1507x; 1.1507x over previous
//
#include <hip/hip_runtime.h>

// CrossingNumberLoss: fraction of edge pairs (i<j) with |cos(angle)| > 0.1.
//
// Brute-force E x E tiled pair count on the vector ALU (K=2 dot -> MFMA useless).
// Each block recomputes normalized edge vectors for its 2048-row strip (registers)
// and 128-col tile (LDS, float2 -> ds_read_b64). Counting via ballot+popcount so
// the accumulate runs on the SALU pipe; per pair the VALU does only mul+fma+cmp.
// Per-wave uniform counts go to d_ws partials (no memset, no atomics).

#define BLK 256              // threads per block
#define WAVES (BLK / 64)
#define IPT 8                // rows per thread
#define ROWS (BLK * IPT)     // 2048 rows per block
#define TJ  128              // cols per block (LDS tile, 1 KiB)
#define THR 0.1f

__device__ __forceinline__ float2 edge_vec(const float* __restrict__ pos,
                                           const int* __restrict__ eidx,
                                           int E, int i) {
    int s = eidx[i];        // edge_index[0][i]
    int t = eidx[E + i];    // edge_index[1][i]
    float dx = pos[2 * t]     - pos[2 * s];
    float dy = pos[2 * t + 1] - pos[2 * s + 1];
    float n  = sqrtf(dx * dx + dy * dy);
    float cn = fmaxf(n, 1e-6f);            // jnp.clip(norm, 1e-6)
    return make_float2(dx / cn, dy / cn);
}

__global__ __launch_bounds__(BLK) void count_kernel(const float* __restrict__ pos,
                                                    const int* __restrict__ eidx,
                                                    unsigned* __restrict__ partials,
                                                    int E) {
    __shared__ float2 tile[TJ];
    int tid = threadIdx.x;
    int rowBase = blockIdx.x * ROWS;
    int colBase = blockIdx.y * TJ;

    // column tile -> LDS (zero vector never counts: |dot| = 0 <= THR)
    if (tid < TJ) {
        int jj = colBase + tid;
        tile[tid] = (jj < E) ? edge_vec(pos, eidx, E, jj) : make_float2(0.f, 0.f);
    }

    // row strip -> registers (8 independent chains per thread)
    float xi[IPT], yi[IPT];
    int   ri[IPT];
#pragma unroll
    for (int k = 0; k < IPT; ++k) {
        ri[k] = rowBase + k * BLK + tid;
        float2 v = (ri[k] < E) ? edge_vec(pos, eidx, E, ri[k]) : make_float2(0.f, 0.f);
        xi[k] = v.x;
        yi[k] = v.y;
    }
    __syncthreads();

    unsigned cnt = 0;   // wave-uniform (ballot/popcount) -> lives in SGPR
    bool hasDiag = (rowBase < colBase + TJ) && (colBase < rowBase + ROWS);
    if (!hasDiag) {
        // hot path: 896 of 1024 blocks
#pragma unroll 4
        for (int j = 0; j < TJ; ++j) {
            float2 c = tile[j];          // one ds_read_b64, wave-broadcast
#pragma unroll
            for (int k = 0; k < IPT; ++k) {
                float d = fmaf(xi[k], c.x, yi[k] * c.y);
                cnt += (unsigned)__popcll(__ballot(fabsf(d) > THR));
            }
        }
    } else {
        // diagonal blocks: exclude j == i inline
#pragma unroll 2
        for (int j = 0; j < TJ; ++j) {
            float2 c = tile[j];
            int jj = colBase + j;
#pragma unroll
            for (int k = 0; k < IPT; ++k) {
                float d = fmaf(xi[k], c.x, yi[k] * c.y);
                cnt += (unsigned)__popcll(__ballot((fabsf(d) > THR) && (jj != ri[k])));
            }
        }
    }

    // one slot per wave, written unconditionally (no zero-init of ws needed)
    if ((tid & 63) == 0) {
        int blockLin = blockIdx.y * gridDim.x + blockIdx.x;
        partials[blockLin * WAVES + (tid >> 6)] = cnt;
    }
}

// Sum 4096 per-wave partials; ordered off-diagonal count u is exactly double
// the i<j count (cos_ij == cos_ji bitwise). result = (u/2) / (E*(E-1)/2).
__global__ __launch_bounds__(256) void finalize_kernel(const unsigned* __restrict__ partials,
                                                       int n, float* __restrict__ out, int E) {
    __shared__ unsigned wsum[4];
    int tid = threadIdx.x;
    unsigned s = 0;
    for (int i = tid; i < n; i += 256) s += partials[i];
    for (int off = 32; off > 0; off >>= 1) s += __shfl_down(s, off);
    if ((tid & 63) == 0) wsum[tid >> 6] = s;
    __syncthreads();
    if (tid == 0) {
        unsigned u = wsum[0] + wsum[1] + wsum[2] + wsum[3];
        double count = (double)u * 0.5;
        double denom = (double)E * (double)(E - 1) * 0.5;
        out[0] = (float)(count / denom);
    }
}

extern "C" void kernel_launch(void* const* d_in, const int* in_sizes, int n_in,
                              void* d_out, int out_size, void* d_ws, size_t ws_size,
                              hipStream_t stream) {
    const float* pos  = (const float*)d_in[0];   // [8192, 2] f32
    const int*   eidx = (const int*)d_in[1];     // [2, E] int32 (harness convention)
    int E = in_sizes[1] / 2;

    unsigned* partials = (unsigned*)d_ws;

    dim3 grid((E + ROWS - 1) / ROWS, (E + TJ - 1) / TJ);
    int nPartials = grid.x * grid.y * WAVES;

    count_kernel<<<grid, BLK, 0, stream>>>(pos, eidx, partials, E);
    finalize_kernel<<<1, 256, 0, stream>>>(partials, nPartials, (float*)d_out, E);
}

// Round 5
// 89.700 us; speedup vs baseline: 1.2962x; 1.1265x over previous
//
#include <hip/hip_runtime.h>

// CrossingNumberLoss: fraction of edge pairs (i<j) with |cos(angle)| > 0.1.
//
// Upper-triangle tiled pair count on the vector ALU (K=2 dot -> MFMA useless).
// E split into strips of 2048 rows; triangular (bi<=bj) mega-blocks, each mega
// split into 32 col-subtiles of 64. Off-diagonal megas: all pairs have j>i,
// counted once with weight 2. Diagonal megas: all ordered i!=j pairs counted
// (exactly even by symmetry), weight 1. final count = sum/2.
// Per pair: v_mul + v_fmac + v_cmp(|.|) + v_addc = 4 VALU, accumulate in 4
// independent counters to break the addc chain. Per-wave partials -> d_ws.

#define BLK 256              // threads per block
#define WAVES (BLK / 64)
#define IPT 8                // rows per thread
#define ROWS (BLK * IPT)     // 2048 rows per strip/block
#define TJ  64               // cols per block (LDS tile, 512 B)
#define SUBS (ROWS / TJ)     // 32 col-subtiles per mega
#define THR 0.1f

__device__ __forceinline__ float2 edge_vec(const float* __restrict__ pos,
                                           const int* __restrict__ eidx,
                                           int E, int i) {
    int s = eidx[i];        // edge_index[0][i]
    int t = eidx[E + i];    // edge_index[1][i]
    float dx = pos[2 * t]     - pos[2 * s];
    float dy = pos[2 * t + 1] - pos[2 * s + 1];
    float n  = sqrtf(dx * dx + dy * dy);
    float cn = fmaxf(n, 1e-6f);            // jnp.clip(norm, 1e-6)
    return make_float2(dx / cn, dy / cn);
}

__global__ __launch_bounds__(BLK) void count_kernel(const float* __restrict__ pos,
                                                    const int* __restrict__ eidx,
                                                    unsigned* __restrict__ partials,
                                                    int E, int nStrip) {
    // decode triangular mega index -> (bi, bj), bi <= bj
    int rem = blockIdx.x, bi = 0, rowlen = nStrip;
    while (rem >= rowlen) { rem -= rowlen; ++bi; --rowlen; }
    int bj = bi + rem;

    int tid = threadIdx.x;
    int rowBase = bi * ROWS;
    int colBase = bj * ROWS + blockIdx.y * TJ;
    bool diag = (bi == bj);

    __shared__ float2 tile[TJ];
    if (tid < TJ) {
        int jj = colBase + tid;
        tile[tid] = (jj < E) ? edge_vec(pos, eidx, E, jj) : make_float2(0.f, 0.f);
    }

    // row strip -> registers (8 independent chains per thread)
    float xi[IPT], yi[IPT];
    int   ri[IPT];
#pragma unroll
    for (int k = 0; k < IPT; ++k) {
        ri[k] = rowBase + k * BLK + tid;
        float2 v = (ri[k] < E) ? edge_vec(pos, eidx, E, ri[k]) : make_float2(0.f, 0.f);
        xi[k] = v.x;
        yi[k] = v.y;
    }
    __syncthreads();

    unsigned acc[4] = {0u, 0u, 0u, 0u};   // statically indexed after unroll
    if (!diag) {
        // hot path: colBase >= rowBase + ROWS, so j > i for every pair
#pragma unroll 4
        for (int j = 0; j < TJ; ++j) {
            float2 c = tile[j];           // ds_read_b64, wave-broadcast
#pragma unroll
            for (int k = 0; k < IPT; ++k) {
                float d = fmaf(xi[k], c.x, yi[k] * c.y);
                acc[k & 3] += (fabsf(d) > THR) ? 1u : 0u;
            }
        }
    } else {
        // diagonal mega: count every ordered pair i != j within the square
#pragma unroll 2
        for (int j = 0; j < TJ; ++j) {
            float2 c = tile[j];
            int jj = colBase + j;
#pragma unroll
            for (int k = 0; k < IPT; ++k) {
                float d = fmaf(xi[k], c.x, yi[k] * c.y);
                acc[k & 3] += ((fabsf(d) > THR) && (jj != ri[k])) ? 1u : 0u;
            }
        }
    }

    unsigned cnt = (acc[0] + acc[1]) + (acc[2] + acc[3]);
    // wave(64) shuffle reduction, wave-uniform result
    for (int off = 32; off > 0; off >>= 1)
        cnt += __shfl_down(cnt, off);
    if ((tid & 63) == 0) {
        int blockLin = blockIdx.y * gridDim.x + blockIdx.x;
        // weight 2 for off-diagonal (unordered, once), 1 for diagonal (ordered)
        partials[blockLin * WAVES + (tid >> 6)] = diag ? cnt : cnt * 2u;
    }
}

// sum of partials u2 = 2*upper_offdiag + diag_ordered (even) -> count = u2/2.
__global__ __launch_bounds__(256) void finalize_kernel(const unsigned* __restrict__ partials,
                                                       int n, float* __restrict__ out, int E) {
    __shared__ unsigned wsum[4];
    int tid = threadIdx.x;
    unsigned s = 0;
    for (int i = tid; i < n; i += 256) s += partials[i];
    for (int off = 32; off > 0; off >>= 1) s += __shfl_down(s, off);
    if ((tid & 63) == 0) wsum[tid >> 6] = s;
    __syncthreads();
    if (tid == 0) {
        unsigned u2 = wsum[0] + wsum[1] + wsum[2] + wsum[3];
        double count = (double)u2 * 0.5;
        double denom = (double)E * (double)(E - 1) * 0.5;
        out[0] = (float)(count / denom);
    }
}

extern "C" void kernel_launch(void* const* d_in, const int* in_sizes, int n_in,
                              void* d_out, int out_size, void* d_ws, size_t ws_size,
                              hipStream_t stream) {
    const float* pos  = (const float*)d_in[0];   // [8192, 2] f32
    const int*   eidx = (const int*)d_in[1];     // [2, E] int32 (harness convention)
    int E = in_sizes[1] / 2;

    unsigned* partials = (unsigned*)d_ws;

    int nStrip = (E + ROWS - 1) / ROWS;          // 8 for E=16384
    int nMega  = nStrip * (nStrip + 1) / 2;      // 36
    dim3 grid(nMega, SUBS);                      // 36 x 32 = 1152 blocks
    int nPartials = nMega * SUBS * WAVES;        // 4608

    count_kernel<<<grid, BLK, 0, stream>>>(pos, eidx, partials, E, nStrip);
    finalize_kernel<<<1, 256, 0, stream>>>(partials, nPartials, (float*)d_out, E);
}

// Round 6
// 83.100 us; speedup vs baseline: 1.3992x; 1.0794x over previous
//
#include <hip/hip_runtime.h>

// CrossingNumberLoss: fraction of edge pairs (i<j) with |cos(angle)| > 0.1.
//
// Phase 1: build normalized edge vectors ev[] once into d_ws (128 KB, L2-resident).
// Phase 2: upper-triangle tiled pair count on the vector ALU (K=2 dot -> MFMA
// useless). E split into strips of 2048 rows; triangular (bi<=bj) megas, each
// split into 32 col-subtiles of 64. Off-diagonal megas: every pair has j>i,
// counted once, weight 2. Diagonal megas: all ordered i!=j pairs (exactly even
// by symmetry), weight 1. final count = sum/2.
// Per pair: v_mul + v_fma + v_cmp(|.|) + v_addc ~= 4 VALU; 4 independent
// accumulators break the carry chain. Per-wave partials -> d_ws (no atomics).

#define BLK 256              // threads per block
#define WAVES (BLK / 64)
#define IPT 8                // rows per thread
#define ROWS (BLK * IPT)     // 2048 rows per strip
#define TJ  64               // cols per block (LDS tile, 512 B)
#define SUBS (ROWS / TJ)     // 32 col-subtiles per mega
#define THR 0.1f

__global__ __launch_bounds__(BLK) void build_ev_kernel(const float* __restrict__ pos,
                                                       const int* __restrict__ eidx,
                                                       float2* __restrict__ ev, int E) {
    int i = blockIdx.x * blockDim.x + threadIdx.x;
    if (i >= E) return;
    int s = eidx[i];        // edge_index[0][i]
    int t = eidx[E + i];    // edge_index[1][i]
    float dx = pos[2 * t]     - pos[2 * s];
    float dy = pos[2 * t + 1] - pos[2 * s + 1];
    float cn = fmaxf(sqrtf(dx * dx + dy * dy), 1e-6f);   // jnp.clip(norm, 1e-6)
    ev[i] = make_float2(dx / cn, dy / cn);
}

__global__ __launch_bounds__(BLK) void count_kernel(const float2* __restrict__ ev,
                                                    unsigned* __restrict__ partials,
                                                    int E, int nStrip) {
    // decode triangular mega index -> (bi, bj), bi <= bj
    int rem = blockIdx.x, bi = 0, rowlen = nStrip;
    while (rem >= rowlen) { rem -= rowlen; ++bi; --rowlen; }
    int bj = bi + rem;

    int tid = threadIdx.x;
    int rowBase = bi * ROWS;
    int colBase = bj * ROWS + blockIdx.y * TJ;
    bool diag = (bi == bj);

    __shared__ float2 tile[TJ];
    if (tid < TJ) {
        int jj = colBase + tid;
        tile[tid] = (jj < E) ? ev[jj] : make_float2(0.f, 0.f);   // coalesced dwordx2
    }

    // row strip -> registers, coalesced global_load_dwordx2 (8 independent chains)
    float xi[IPT], yi[IPT];
    int   ri[IPT];
#pragma unroll
    for (int k = 0; k < IPT; ++k) {
        ri[k] = rowBase + k * BLK + tid;
        float2 v = (ri[k] < E) ? ev[ri[k]] : make_float2(0.f, 0.f);
        xi[k] = v.x;
        yi[k] = v.y;
    }
    __syncthreads();

    unsigned acc[4] = {0u, 0u, 0u, 0u};   // statically indexed after unroll
    if (!diag) {
        // hot path: colBase >= rowBase + ROWS, so j > i for every pair
#pragma unroll 4
        for (int j = 0; j < TJ; ++j) {
            float2 c = tile[j];           // ds_read_b64, wave-broadcast
#pragma unroll
            for (int k = 0; k < IPT; ++k) {
                float d = fmaf(xi[k], c.x, yi[k] * c.y);
                acc[k & 3] += (fabsf(d) > THR) ? 1u : 0u;
            }
        }
    } else {
        // diagonal mega: count every ordered pair i != j within the square
#pragma unroll 2
        for (int j = 0; j < TJ; ++j) {
            float2 c = tile[j];
            int jj = colBase + j;
#pragma unroll
            for (int k = 0; k < IPT; ++k) {
                float d = fmaf(xi[k], c.x, yi[k] * c.y);
                acc[k & 3] += ((fabsf(d) > THR) && (jj != ri[k])) ? 1u : 0u;
            }
        }
    }

    unsigned cnt = (acc[0] + acc[1]) + (acc[2] + acc[3]);
    // wave(64) shuffle reduction -> wave-uniform
    for (int off = 32; off > 0; off >>= 1)
        cnt += __shfl_down(cnt, off);
    if ((tid & 63) == 0) {
        int blockLin = blockIdx.y * gridDim.x + blockIdx.x;
        // weight 2 off-diagonal (unordered, counted once), 1 diagonal (ordered)
        partials[blockLin * WAVES + (tid >> 6)] = diag ? cnt : cnt * 2u;
    }
}

// sum u2 = 2*upper_offdiag + diag_ordered (even) -> count = u2/2.
__global__ __launch_bounds__(256) void finalize_kernel(const unsigned* __restrict__ partials,
                                                       int n, float* __restrict__ out, int E) {
    __shared__ unsigned wsum[4];
    int tid = threadIdx.x;
    unsigned s = 0;
    for (int i = tid; i < n; i += 256) s += partials[i];
    for (int off = 32; off > 0; off >>= 1) s += __shfl_down(s, off);
    if ((tid & 63) == 0) wsum[tid >> 6] = s;
    __syncthreads();
    if (tid == 0) {
        unsigned u2 = wsum[0] + wsum[1] + wsum[2] + wsum[3];
        double count = (double)u2 * 0.5;
        double denom = (double)E * (double)(E - 1) * 0.5;
        out[0] = (float)(count / denom);
    }
}

extern "C" void kernel_launch(void* const* d_in, const int* in_sizes, int n_in,
                              void* d_out, int out_size, void* d_ws, size_t ws_size,
                              hipStream_t stream) {
    const float* pos  = (const float*)d_in[0];   // [8192, 2] f32
    const int*   eidx = (const int*)d_in[1];     // [2, E] int32 (harness convention)
    int E = in_sizes[1] / 2;

    // ws layout: ev[] at offset 0 (E*8 bytes), partials at +1 MB
    float2*   ev       = (float2*)d_ws;
    unsigned* partials = (unsigned*)((char*)d_ws + (1u << 20));

    int nStrip = (E + ROWS - 1) / ROWS;          // 8 for E=16384
    int nMega  = nStrip * (nStrip + 1) / 2;      // 36
    dim3 grid(nMega, SUBS);                      // 36 x 32 = 1152 blocks
    int nPartials = nMega * SUBS * WAVES;        // 4608

    build_ev_kernel<<<(E + BLK - 1) / BLK, BLK, 0, stream>>>(pos, eidx, ev, E);
    count_kernel<<<grid, BLK, 0, stream>>>(ev, partials, E, nStrip);
    finalize_kernel<<<1, 256, 0, stream>>>(partials, nPartials, (float*)d_out, E);
}